// Round 7
// baseline (285.320 us; speedup 1.0000x reference)
//
#include <hip/hip_runtime.h>
#include <hip/hip_bf16.h>
#include <cmath>

// GATv2 encoder, 3 layers, d=64, f32 in/out.
//   1. dst-CSR build via two-level partition (coarse 1024-dst buckets ->
//      per-coarse-bucket fine CSR; csr_src stored as ushort).
//   2. per layer: transform (xlh = bf16(h@Wl+bl) gather table, xr = h@Wr+br),
//      then edge aggregation: ONE NODE PER WAVE, 8 lanes per edge (uint4 = 8
//      bf16 per lane), 16-edge chunks, online softmax with one 6-shfl
//      max/sum chain per chunk, fused bias+ReLU+residual.

#define D 64
#define CB 10              // coarse bucket = 1024 dsts (dst >> CB); N <= 65536
#define NBLK 512           // persistent blocks for coarse hist/scatter

// ---------------- CSR build ----------------

// C1: per-block coarse histogram. ghist[c*NBLK + blk] = count.
__global__ __launch_bounds__(256) void hist_coarse_kernel(
    const int* __restrict__ ei, int* __restrict__ ghist, int E, int N, int NC) {
  __shared__ int h[64];
  int tid = threadIdx.x, blk = blockIdx.x;
  if (tid < 64) h[tid] = 0;
  __syncthreads();
  for (int eid = blk * 256 + tid; eid < E + N; eid += NBLK * 256) {
    int d = (eid < E) ? ei[E + eid] : (eid - E);
    atomicAdd(&h[d >> CB], 1);
  }
  __syncthreads();
  if (tid < NC) ghist[tid * NBLK + blk] = h[tid];
}

// C2: exclusive scan of M = NC*NBLK counts in place; emit cbase[c] (+ cbase[NC]).
__global__ __launch_bounds__(1024) void scan_coarse_kernel(
    int* __restrict__ g, int* __restrict__ cbase, int M, int NC, int EP) {
  int tid = threadIdx.x;
  int chunk = (M + 1023) / 1024;
  int beg = tid * chunk;
  int end = min(M, beg + chunk);
  int sum = 0;
  for (int i = beg; i < end; ++i) sum += g[i];
  int lane = tid & 63, w = tid >> 6;
  int v = sum;
#pragma unroll
  for (int o = 1; o < 64; o <<= 1) {
    int t = __shfl_up(v, o, 64);
    if (lane >= o) v += t;
  }
  __shared__ int wsum[16], woff[16];
  if (lane == 63) wsum[w] = v;
  __syncthreads();
  if (tid == 0) { int r = 0; for (int i = 0; i < 16; ++i) { woff[i] = r; r += wsum[i]; } }
  __syncthreads();
  int run = woff[w] + (v - sum);
  for (int i = beg; i < end; ++i) {
    int old = g[i];
    g[i] = run;
    if ((i & (NBLK - 1)) == 0) cbase[i / NBLK] = run;
    run += old;
  }
  if (tid == 0) cbase[NC] = EP;
}

// C3: coarse scatter; per-(block,bucket) runs are contiguous -> full-line writes.
// rec = (dst&1023)<<16 | src.
__global__ __launch_bounds__(256) void scatter_coarse_kernel(
    const int* __restrict__ ei, const int* __restrict__ g,
    unsigned* __restrict__ rec, int E, int N, int NC) {
  __shared__ int cur[64];
  int tid = threadIdx.x, blk = blockIdx.x;
  if (tid < NC) cur[tid] = g[tid * NBLK + blk];
  __syncthreads();
  for (int eid = blk * 256 + tid; eid < E + N; eid += NBLK * 256) {
    int s, d;
    if (eid < E) { s = ei[eid]; d = ei[E + eid]; }
    else         { s = d = eid - E; }
    int pos = atomicAdd(&cur[d >> CB], 1);
    rec[pos] = ((unsigned)(d & ((1 << CB) - 1)) << 16) | (unsigned)s;
  }
}

// C4: one block per coarse bucket: LDS hist of 1024 dsts -> scan -> rowptr +
// scatter (ushort src) within the bucket's contiguous (L2-local) region.
__global__ __launch_bounds__(1024) void buildcsr2_kernel(
    const unsigned* __restrict__ rec, const int* __restrict__ cbase,
    int* __restrict__ rowptr, unsigned short* __restrict__ csr_src,
    int N, int EP) {
  int c = blockIdx.x, tid = threadIdx.x;
  int bb = cbase[c], be = cbase[c + 1];
  __shared__ int hist[1024], cur[1024];
  hist[tid] = 0;
  __syncthreads();
  for (int p = bb + tid; p < be; p += 1024)
    atomicAdd(&hist[rec[p] >> 16], 1);
  __syncthreads();
  int dv = hist[tid];
  int lane = tid & 63, w = tid >> 6;
  int inc = dv;
#pragma unroll
  for (int o = 1; o < 64; o <<= 1) {
    int t = __shfl_up(inc, o, 64);
    if (lane >= o) inc += t;
  }
  __shared__ int wsum[16], woff[16];
  if (lane == 63) wsum[w] = inc;
  __syncthreads();
  if (tid == 0) { int r = 0; for (int i = 0; i < 16; ++i) { woff[i] = r; r += wsum[i]; } }
  __syncthreads();
  int excl = woff[w] + inc - dv;
  cur[tid] = excl;
  int node = (c << CB) + tid;
  if (node < N) rowptr[node] = bb + excl;
  if (c == 0 && tid == 0) rowptr[N] = EP;
  __syncthreads();
  for (int p = bb + tid; p < be; p += 1024) {
    unsigned r = rec[p];
    int pos = bb + atomicAdd(&cur[r >> 16], 1);
    csr_src[pos] = (unsigned short)(r & 0xFFFFu);
  }
}

// ---------------- transform: xlh = bf16(h@Wl+bl), xr = h@Wr+br ----------------

__device__ __forceinline__ unsigned short f2bf(float f) {
  unsigned u = __float_as_uint(f);
  return (unsigned short)((u + 0x7FFFu + ((u >> 16) & 1u)) >> 16);  // RNE
}

__global__ __launch_bounds__(256) void transform_kernel(
    const float* __restrict__ h,
    const float* __restrict__ Wl, const float* __restrict__ bl,
    const float* __restrict__ Wr, const float* __restrict__ br,
    unsigned short* __restrict__ xlh, float* __restrict__ xr, int N) {
  __shared__ float hs[16][D];
  int tid = threadIdx.x;
  int j = tid & 63;
  float wl[D], wr[D];
#pragma unroll
  for (int k = 0; k < D; ++k) {
    wl[k] = Wl[k * D + j];
    wr[k] = Wr[k * D + j];
  }
  int node0 = blockIdx.x * 16;
  for (int i = tid; i < 16 * D; i += 256) {
    int n = node0 + (i >> 6);
    hs[i >> 6][i & 63] = (n < N) ? h[(size_t)n * D + (i & 63)] : 0.f;
  }
  __syncthreads();
  float blj = bl[j], brj = br[j];
  int nl = tid >> 6;
  for (int g = 0; g < 4; ++g) {
    int local = nl * 4 + g;
    int n = node0 + local;
    float al = blj, ar = brj;
#pragma unroll
    for (int k4 = 0; k4 < D / 4; ++k4) {
      float4 hv = *reinterpret_cast<const float4*>(&hs[local][k4 * 4]);
      al = fmaf(hv.x, wl[k4 * 4 + 0], al);
      ar = fmaf(hv.x, wr[k4 * 4 + 0], ar);
      al = fmaf(hv.y, wl[k4 * 4 + 1], al);
      ar = fmaf(hv.y, wr[k4 * 4 + 1], ar);
      al = fmaf(hv.z, wl[k4 * 4 + 2], al);
      ar = fmaf(hv.z, wr[k4 * 4 + 2], ar);
      al = fmaf(hv.w, wl[k4 * 4 + 3], al);
      ar = fmaf(hv.w, wr[k4 * 4 + 3], ar);
    }
    if (n < N) {
      xlh[(size_t)n * D + j] = f2bf(al);
      xr[(size_t)n * D + j] = ar;
    }
  }
}

// ---------------- edge aggregation ----------------
// One NODE per 64-lane wave. Lane = (j8 = lane>>3 edge slot, f8 = lane&7
// feature octet). 16-edge chunks: 2 uint4 gathers/lane (edges j8, j8+8).
// Online softmax: one {3-shfl dot} per slot + one {3-shfl max + 3-shfl sum}
// chain per 16 edges. deg is wave-uniform -> no intra-wave imbalance.

__device__ __forceinline__ float bflo(unsigned u) { return __uint_as_float(u << 16); }
__device__ __forceinline__ float bfhi(unsigned u) { return __uint_as_float(u & 0xFFFF0000u); }

__global__ __launch_bounds__(256) void edge_kernel(
    const unsigned short* __restrict__ xlh, const float* __restrict__ xr,
    const float* __restrict__ h_in, const int* __restrict__ rowptr,
    const unsigned short* __restrict__ csr_src, const float* __restrict__ att,
    const float* __restrict__ bias, float* __restrict__ h_out, int N) {
  int v = (blockIdx.x * blockDim.x + threadIdx.x) >> 6;
  if (v >= N) return;
  int lane = threadIdx.x & 63;
  int j8 = lane >> 3, f8 = lane & 7;
  const float* xrp = &xr[(size_t)v * D + f8 * 8];
  float4 xrA = *reinterpret_cast<const float4*>(xrp);
  float4 xrB = *reinterpret_cast<const float4*>(xrp + 4);
  float4 atA = *reinterpret_cast<const float4*>(&att[f8 * 8]);
  float4 atB = *reinterpret_cast<const float4*>(&att[f8 * 8 + 4]);
  int beg = rowptr[v], end = rowptr[v + 1];
  int deg = end - beg;                       // >= 1 (self-loop)
  float m = -INFINITY, s = 0.f;
  float4 acc0 = make_float4(0.f, 0.f, 0.f, 0.f);
  float4 acc1 = make_float4(0.f, 0.f, 0.f, 0.f);
  for (int base = 0; base < deg; base += 64) {
    int us = csr_src[min(beg + base + lane, end - 1)];   // 64 srcs, coalesced
    int nb = min(64, deg - base);
    for (int sc = 0; sc < nb; sc += 16) {
      int j0 = sc + j8, j1 = sc + 8 + j8;
      int u0 = __shfl(us, j0, 64);
      int u1 = __shfl(us, j1, 64);
      uint4 q0 = *reinterpret_cast<const uint4*>(&xlh[(size_t)u0 * D + f8 * 8]);
      uint4 q1 = *reinterpret_cast<const uint4*>(&xlh[(size_t)u1 * D + f8 * 8]);
      // partial dots (per lane: 8 features of its slot's edge)
      float t0, t1, t2, t3, t4, t5, t6, t7, p0, p1;
      t0 = bflo(q0.x) + xrA.x; t1 = bfhi(q0.x) + xrA.y;
      t2 = bflo(q0.y) + xrA.z; t3 = bfhi(q0.y) + xrA.w;
      t4 = bflo(q0.z) + xrB.x; t5 = bfhi(q0.z) + xrB.y;
      t6 = bflo(q0.w) + xrB.z; t7 = bfhi(q0.w) + xrB.w;
      t0 = fmaxf(t0, 0.2f * t0); t1 = fmaxf(t1, 0.2f * t1);
      t2 = fmaxf(t2, 0.2f * t2); t3 = fmaxf(t3, 0.2f * t3);
      t4 = fmaxf(t4, 0.2f * t4); t5 = fmaxf(t5, 0.2f * t5);
      t6 = fmaxf(t6, 0.2f * t6); t7 = fmaxf(t7, 0.2f * t7);
      p0 = t0 * atA.x; p0 = fmaf(t1, atA.y, p0);
      p0 = fmaf(t2, atA.z, p0); p0 = fmaf(t3, atA.w, p0);
      p0 = fmaf(t4, atB.x, p0); p0 = fmaf(t5, atB.y, p0);
      p0 = fmaf(t6, atB.z, p0); p0 = fmaf(t7, atB.w, p0);
      t0 = bflo(q1.x) + xrA.x; t1 = bfhi(q1.x) + xrA.y;
      t2 = bflo(q1.y) + xrA.z; t3 = bfhi(q1.y) + xrA.w;
      t4 = bflo(q1.z) + xrB.x; t5 = bfhi(q1.z) + xrB.y;
      t6 = bflo(q1.w) + xrB.z; t7 = bfhi(q1.w) + xrB.w;
      t0 = fmaxf(t0, 0.2f * t0); t1 = fmaxf(t1, 0.2f * t1);
      t2 = fmaxf(t2, 0.2f * t2); t3 = fmaxf(t3, 0.2f * t3);
      t4 = fmaxf(t4, 0.2f * t4); t5 = fmaxf(t5, 0.2f * t5);
      t6 = fmaxf(t6, 0.2f * t6); t7 = fmaxf(t7, 0.2f * t7);
      p1 = t0 * atA.x; p1 = fmaf(t1, atA.y, p1);
      p1 = fmaf(t2, atA.z, p1); p1 = fmaf(t3, atA.w, p1);
      p1 = fmaf(t4, atB.x, p1); p1 = fmaf(t5, atB.y, p1);
      p1 = fmaf(t6, atB.z, p1); p1 = fmaf(t7, atB.w, p1);
      // reduce dots over f8 (8 lanes per edge)
      p0 += __shfl_xor(p0, 1, 64); p1 += __shfl_xor(p1, 1, 64);
      p0 += __shfl_xor(p0, 2, 64); p1 += __shfl_xor(p1, 2, 64);
      p0 += __shfl_xor(p0, 4, 64); p1 += __shfl_xor(p1, 4, 64);
      p0 = (j0 < nb) ? p0 : -INFINITY;
      p1 = (j1 < nb) ? p1 : -INFINITY;
      // chunk max over the 8 edge slots
      float cm = fmaxf(p0, p1);
      cm = fmaxf(cm, __shfl_xor(cm, 8, 64));
      cm = fmaxf(cm, __shfl_xor(cm, 16, 64));
      cm = fmaxf(cm, __shfl_xor(cm, 32, 64));
      float mn = fmaxf(m, cm);
      float a  = __expf(m - mn);             // first chunk: exp(-inf)=0
      float w0 = __expf(p0 - mn);            // invalid -> 0
      float w1 = __expf(p1 - mn);
      float sw = w0 + w1;
      sw += __shfl_xor(sw, 8, 64);
      sw += __shfl_xor(sw, 16, 64);
      sw += __shfl_xor(sw, 32, 64);
      s = s * a + sw;
      acc0.x = fmaf(w0, bflo(q0.x), fmaf(w1, bflo(q1.x), acc0.x * a));
      acc0.y = fmaf(w0, bfhi(q0.x), fmaf(w1, bfhi(q1.x), acc0.y * a));
      acc0.z = fmaf(w0, bflo(q0.y), fmaf(w1, bflo(q1.y), acc0.z * a));
      acc0.w = fmaf(w0, bfhi(q0.y), fmaf(w1, bfhi(q1.y), acc0.w * a));
      acc1.x = fmaf(w0, bflo(q0.z), fmaf(w1, bflo(q1.z), acc1.x * a));
      acc1.y = fmaf(w0, bfhi(q0.z), fmaf(w1, bfhi(q1.z), acc1.y * a));
      acc1.z = fmaf(w0, bflo(q0.w), fmaf(w1, bflo(q1.w), acc1.z * a));
      acc1.w = fmaf(w0, bfhi(q0.w), fmaf(w1, bfhi(q1.w), acc1.w * a));
      m = mn;
    }
  }
  // reduce accumulators over the 8 edge slots (j dimension)
#pragma unroll
  for (int o = 8; o < 64; o <<= 1) {
    acc0.x += __shfl_xor(acc0.x, o, 64);
    acc0.y += __shfl_xor(acc0.y, o, 64);
    acc0.z += __shfl_xor(acc0.z, o, 64);
    acc0.w += __shfl_xor(acc0.w, o, 64);
    acc1.x += __shfl_xor(acc1.x, o, 64);
    acc1.y += __shfl_xor(acc1.y, o, 64);
    acc1.z += __shfl_xor(acc1.z, o, 64);
    acc1.w += __shfl_xor(acc1.w, o, 64);
  }
  if (j8 == 0) {                            // lanes 0..7: f8 = lane
    float inv = 1.f / s;
    const float* bp = &bias[lane * 8];
    const float* hp = &h_in[(size_t)v * D + lane * 8];
    float4 bA = *reinterpret_cast<const float4*>(bp);
    float4 bB = *reinterpret_cast<const float4*>(bp + 4);
    float4 hA = *reinterpret_cast<const float4*>(hp);
    float4 hB = *reinterpret_cast<const float4*>(hp + 4);
    float4 oA, oB;
    oA.x = fmaxf(acc0.x * inv + bA.x, 0.f) + hA.x;
    oA.y = fmaxf(acc0.y * inv + bA.y, 0.f) + hA.y;
    oA.z = fmaxf(acc0.z * inv + bA.z, 0.f) + hA.z;
    oA.w = fmaxf(acc0.w * inv + bA.w, 0.f) + hA.w;
    oB.x = fmaxf(acc1.x * inv + bB.x, 0.f) + hB.x;
    oB.y = fmaxf(acc1.y * inv + bB.y, 0.f) + hB.y;
    oB.z = fmaxf(acc1.z * inv + bB.z, 0.f) + hB.z;
    oB.w = fmaxf(acc1.w * inv + bB.w, 0.f) + hB.w;
    float* op = &h_out[(size_t)v * D + lane * 8];
    *reinterpret_cast<float4*>(op) = oA;
    *reinterpret_cast<float4*>(op + 4) = oB;
  }
}

// ---------------- launch ----------------

extern "C" void kernel_launch(void* const* d_in, const int* in_sizes, int n_in,
                              void* d_out, int out_size, void* d_ws, size_t ws_size,
                              hipStream_t stream) {
  const float* x    = (const float*)d_in[0];
  const int*   ei   = (const int*)d_in[1];
  const float* Wl   = (const float*)d_in[2];
  const float* bl   = (const float*)d_in[3];
  const float* Wr   = (const float*)d_in[4];
  const float* br   = (const float*)d_in[5];
  const float* att  = (const float*)d_in[6];
  const float* bias = (const float*)d_in[7];

  int N = in_sizes[0] / D;
  int E = in_sizes[1] / 2;
  int L = in_sizes[2] / (D * D);
  int EP = E + N;
  int NC = (N + (1 << CB) - 1) >> CB;   // coarse buckets (<= 64)
  int M = NC * NBLK;

  float* xr = (float*)d_ws;
  float* hA = xr + (size_t)N * D;
  float* hB = hA + (size_t)N * D;
  unsigned short* xlh = (unsigned short*)(hB + (size_t)N * D);
  unsigned* rec = (unsigned*)(xlh + (size_t)N * D);
  unsigned short* csr_src = (unsigned short*)(rec + EP);
  int* rowptr   = (int*)(csr_src + ((EP + 1) & ~1));
  int* ghist    = rowptr + (N + 1);
  int* cbase    = ghist + M;

  // CSR build (graph is layer-invariant: build once per call; every ghist/cbase
  // slot is written each call, so no memset needed)
  hist_coarse_kernel<<<NBLK, 256, 0, stream>>>(ei, ghist, E, N, NC);
  scan_coarse_kernel<<<1, 1024, 0, stream>>>(ghist, cbase, M, NC, EP);
  scatter_coarse_kernel<<<NBLK, 256, 0, stream>>>(ei, ghist, rec, E, N, NC);
  buildcsr2_kernel<<<NC, 1024, 0, stream>>>(rec, cbase, rowptr, csr_src, N, EP);

  int nblocks = (N + 3) / 4;                // one node per wave, 4 waves/block
  const float* h_in = x;
  for (int l = 0; l < L; ++l) {
    float* h_out = (l == L - 1) ? (float*)d_out : ((l % 2 == 0) ? hA : hB);
    transform_kernel<<<(N + 15) / 16, 256, 0, stream>>>(
        h_in, Wl + (size_t)l * D * D, bl + (size_t)l * D,
        Wr + (size_t)l * D * D, br + (size_t)l * D, xlh, xr, N);
    edge_kernel<<<nblocks, 256, 0, stream>>>(
        xlh, xr, h_in, rowptr, csr_src, att + (size_t)l * D,
        bias + (size_t)l * D, h_out, N);
    h_in = h_out;
  }
}

// Round 8
// 218.587 us; speedup vs baseline: 1.3053x; 1.3053x over previous
//
#include <hip/hip_runtime.h>
#include <hip/hip_bf16.h>
#include <cmath>

// GATv2 encoder, 3 layers, d=64, f32 in/out.
//   1. dst-CSR build via two-level partition (coarse 1024-dst buckets ->
//      per-coarse-bucket fine CSR; csr_src stored as ushort).
//   2. per layer: transform (xlh/xrh = bf16(h@W+b) tables), then edge
//      aggregation: 4 nodes/wave, 16-lane groups, group-local online softmax
//      over 4-edge chunks, bf16 gathers, prefetched indices, fused
//      bias+ReLU+residual.
// Edge kernel is bound by L2-capacity misses on the 6.4MB xlh gather table
// (per-XCD L2 = 4MB, replicated) + the per-node streams; bf16 xr trims the
// stream side.

#define D 64
#define CB 10              // coarse bucket = 1024 dsts (dst >> CB); N <= 65536
#define NBLK 512           // persistent blocks for coarse hist/scatter

// ---------------- CSR build ----------------

// C1: per-block coarse histogram. ghist[c*NBLK + blk] = count.
__global__ __launch_bounds__(256) void hist_coarse_kernel(
    const int* __restrict__ ei, int* __restrict__ ghist, int E, int N, int NC) {
  __shared__ int h[64];
  int tid = threadIdx.x, blk = blockIdx.x;
  if (tid < 64) h[tid] = 0;
  __syncthreads();
  for (int eid = blk * 256 + tid; eid < E + N; eid += NBLK * 256) {
    int d = (eid < E) ? ei[E + eid] : (eid - E);
    atomicAdd(&h[d >> CB], 1);
  }
  __syncthreads();
  if (tid < NC) ghist[tid * NBLK + blk] = h[tid];
}

// C2: exclusive scan of M = NC*NBLK counts in place; emit cbase[c] (+ cbase[NC]).
__global__ __launch_bounds__(1024) void scan_coarse_kernel(
    int* __restrict__ g, int* __restrict__ cbase, int M, int NC, int EP) {
  int tid = threadIdx.x;
  int chunk = (M + 1023) / 1024;
  int beg = tid * chunk;
  int end = min(M, beg + chunk);
  int sum = 0;
  for (int i = beg; i < end; ++i) sum += g[i];
  int lane = tid & 63, w = tid >> 6;
  int v = sum;
#pragma unroll
  for (int o = 1; o < 64; o <<= 1) {
    int t = __shfl_up(v, o, 64);
    if (lane >= o) v += t;
  }
  __shared__ int wsum[16], woff[16];
  if (lane == 63) wsum[w] = v;
  __syncthreads();
  if (tid == 0) { int r = 0; for (int i = 0; i < 16; ++i) { woff[i] = r; r += wsum[i]; } }
  __syncthreads();
  int run = woff[w] + (v - sum);
  for (int i = beg; i < end; ++i) {
    int old = g[i];
    g[i] = run;
    if ((i & (NBLK - 1)) == 0) cbase[i / NBLK] = run;
    run += old;
  }
  if (tid == 0) cbase[NC] = EP;
}

// C3: coarse scatter; per-(block,bucket) runs are contiguous -> full-line writes.
// rec = (dst&1023)<<16 | src.
__global__ __launch_bounds__(256) void scatter_coarse_kernel(
    const int* __restrict__ ei, const int* __restrict__ g,
    unsigned* __restrict__ rec, int E, int N, int NC) {
  __shared__ int cur[64];
  int tid = threadIdx.x, blk = blockIdx.x;
  if (tid < NC) cur[tid] = g[tid * NBLK + blk];
  __syncthreads();
  for (int eid = blk * 256 + tid; eid < E + N; eid += NBLK * 256) {
    int s, d;
    if (eid < E) { s = ei[eid]; d = ei[E + eid]; }
    else         { s = d = eid - E; }
    int pos = atomicAdd(&cur[d >> CB], 1);
    rec[pos] = ((unsigned)(d & ((1 << CB) - 1)) << 16) | (unsigned)s;
  }
}

// C4: one block per coarse bucket: LDS hist of 1024 dsts -> scan -> rowptr +
// scatter (ushort src) within the bucket's contiguous (L2-local) region.
__global__ __launch_bounds__(1024) void buildcsr2_kernel(
    const unsigned* __restrict__ rec, const int* __restrict__ cbase,
    int* __restrict__ rowptr, unsigned short* __restrict__ csr_src,
    int N, int EP) {
  int c = blockIdx.x, tid = threadIdx.x;
  int bb = cbase[c], be = cbase[c + 1];
  __shared__ int hist[1024], cur[1024];
  hist[tid] = 0;
  __syncthreads();
  for (int p = bb + tid; p < be; p += 1024)
    atomicAdd(&hist[rec[p] >> 16], 1);
  __syncthreads();
  int dv = hist[tid];
  int lane = tid & 63, w = tid >> 6;
  int inc = dv;
#pragma unroll
  for (int o = 1; o < 64; o <<= 1) {
    int t = __shfl_up(inc, o, 64);
    if (lane >= o) inc += t;
  }
  __shared__ int wsum[16], woff[16];
  if (lane == 63) wsum[w] = inc;
  __syncthreads();
  if (tid == 0) { int r = 0; for (int i = 0; i < 16; ++i) { woff[i] = r; r += wsum[i]; } }
  __syncthreads();
  int excl = woff[w] + inc - dv;
  cur[tid] = excl;
  int node = (c << CB) + tid;
  if (node < N) rowptr[node] = bb + excl;
  if (c == 0 && tid == 0) rowptr[N] = EP;
  __syncthreads();
  for (int p = bb + tid; p < be; p += 1024) {
    unsigned r = rec[p];
    int pos = bb + atomicAdd(&cur[r >> 16], 1);
    csr_src[pos] = (unsigned short)(r & 0xFFFFu);
  }
}

// ---------------- transform: xlh = bf16(h@Wl+bl), xrh = bf16(h@Wr+br) -------

__device__ __forceinline__ unsigned short f2bf(float f) {
  unsigned u = __float_as_uint(f);
  return (unsigned short)((u + 0x7FFFu + ((u >> 16) & 1u)) >> 16);  // RNE
}
__device__ __forceinline__ float bflo(unsigned u) { return __uint_as_float(u << 16); }
__device__ __forceinline__ float bfhi(unsigned u) { return __uint_as_float(u & 0xFFFF0000u); }

__global__ __launch_bounds__(256) void transform_kernel(
    const float* __restrict__ h,
    const float* __restrict__ Wl, const float* __restrict__ bl,
    const float* __restrict__ Wr, const float* __restrict__ br,
    unsigned short* __restrict__ xlh, unsigned short* __restrict__ xrh, int N) {
  __shared__ float hs[16][D];
  int tid = threadIdx.x;
  int j = tid & 63;
  float wl[D], wr[D];
#pragma unroll
  for (int k = 0; k < D; ++k) {
    wl[k] = Wl[k * D + j];
    wr[k] = Wr[k * D + j];
  }
  int node0 = blockIdx.x * 16;
  for (int i = tid; i < 16 * D; i += 256) {
    int n = node0 + (i >> 6);
    hs[i >> 6][i & 63] = (n < N) ? h[(size_t)n * D + (i & 63)] : 0.f;
  }
  __syncthreads();
  float blj = bl[j], brj = br[j];
  int nl = tid >> 6;
  for (int g = 0; g < 4; ++g) {
    int local = nl * 4 + g;
    int n = node0 + local;
    float al = blj, ar = brj;
#pragma unroll
    for (int k4 = 0; k4 < D / 4; ++k4) {
      float4 hv = *reinterpret_cast<const float4*>(&hs[local][k4 * 4]);
      al = fmaf(hv.x, wl[k4 * 4 + 0], al);
      ar = fmaf(hv.x, wr[k4 * 4 + 0], ar);
      al = fmaf(hv.y, wl[k4 * 4 + 1], al);
      ar = fmaf(hv.y, wr[k4 * 4 + 1], ar);
      al = fmaf(hv.z, wl[k4 * 4 + 2], al);
      ar = fmaf(hv.z, wr[k4 * 4 + 2], ar);
      al = fmaf(hv.w, wl[k4 * 4 + 3], al);
      ar = fmaf(hv.w, wr[k4 * 4 + 3], ar);
    }
    if (n < N) {
      xlh[(size_t)n * D + j] = f2bf(al);
      xrh[(size_t)n * D + j] = f2bf(ar);
    }
  }
}

// ---------------- edge aggregation ----------------
// Wave = 4 nodes; 16-lane group per node (float4 features/lane, bf16 gathers).
// Per group: online softmax over 4-edge chunks (4 gathers in flight),
// src indices (ushort) prefetched 16 ahead. Fused bias+ReLU+residual.

__global__ __launch_bounds__(256) void edge_kernel(
    const unsigned short* __restrict__ xlh, const unsigned short* __restrict__ xrh,
    const float* __restrict__ h_in, const int* __restrict__ rowptr,
    const unsigned short* __restrict__ csr_src, const float* __restrict__ att,
    const float* __restrict__ bias, float* __restrict__ h_out, int N) {
  int wv = (blockIdx.x * blockDim.x + threadIdx.x) >> 6;
  int lane = threadIdx.x & 63;
  int g = lane >> 4, l16 = lane & 15;
  int v = wv * 4 + g;
  if (v >= N) return;
  uint2 xq = *reinterpret_cast<const uint2*>(&xrh[(size_t)v * D + l16 * 4]);
  float4 xr4;
  xr4.x = bflo(xq.x); xr4.y = bfhi(xq.x);
  xr4.z = bflo(xq.y); xr4.w = bfhi(xq.y);
  float4 at4 = *reinterpret_cast<const float4*>(&att[l16 * 4]);
  int beg = rowptr[v], end = rowptr[v + 1];
  int deg = end - beg;                       // >= 1 (self-loop)
  int glane0 = g << 4;
  float m = -INFINITY, s = 0.f;
  float ax = 0.f, ay = 0.f, az = 0.f, aw = 0.f;
  int us = csr_src[min(beg + l16, end - 1)]; // first 16 srcs (coalesced)
  for (int sc = 0; sc < deg; sc += 16) {
    int us_cur = us;
    if (sc + 16 < deg)                       // prefetch next batch's indices
      us = csr_src[min(beg + sc + 16 + l16, end - 1)];
    int nt = min(16, deg - sc);
    for (int cc = 0; cc < nt; cc += 4) {
      float4 xu[4];
      float p[4];
#pragma unroll
      for (int k = 0; k < 4; ++k) {
        int u = __shfl(us_cur, glane0 + cc + k, 64);   // group-local broadcast
        uint2 q = *reinterpret_cast<const uint2*>(&xlh[(size_t)u * D + l16 * 4]);
        xu[k].x = bflo(q.x);
        xu[k].y = bfhi(q.x);
        xu[k].z = bflo(q.y);
        xu[k].w = bfhi(q.y);
        float tx = xu[k].x + xr4.x, ty = xu[k].y + xr4.y;
        float tz = xu[k].z + xr4.z, tw = xu[k].w + xr4.w;
        tx = fmaxf(tx, 0.2f * tx);                     // leaky_relu slope 0.2
        ty = fmaxf(ty, 0.2f * ty);
        tz = fmaxf(tz, 0.2f * tz);
        tw = fmaxf(tw, 0.2f * tw);
        float pp = tx * at4.x;
        pp = fmaf(ty, at4.y, pp);
        pp = fmaf(tz, at4.z, pp);
        pp = fmaf(tw, at4.w, pp);
        pp += __shfl_xor(pp, 1, 64);                   // 16-lane group reduce
        pp += __shfl_xor(pp, 2, 64);
        pp += __shfl_xor(pp, 4, 64);
        pp += __shfl_xor(pp, 8, 64);
        p[k] = (cc + k < nt) ? pp : -INFINITY;
      }
      float pm = fmaxf(fmaxf(p[0], p[1]), fmaxf(p[2], p[3]));
      float mn = fmaxf(m, pm);
      float a  = __expf(m - mn);                       // first chunk: exp(-inf)=0
      float w0 = __expf(p[0] - mn);                    // invalid -> 0
      float w1 = __expf(p[1] - mn);
      float w2 = __expf(p[2] - mn);
      float w3 = __expf(p[3] - mn);
      s = s * a + (w0 + w1) + (w2 + w3);
      ax = fmaf(w0, xu[0].x, fmaf(w1, xu[1].x, fmaf(w2, xu[2].x, fmaf(w3, xu[3].x, ax * a))));
      ay = fmaf(w0, xu[0].y, fmaf(w1, xu[1].y, fmaf(w2, xu[2].y, fmaf(w3, xu[3].y, ay * a))));
      az = fmaf(w0, xu[0].z, fmaf(w1, xu[1].z, fmaf(w2, xu[2].z, fmaf(w3, xu[3].z, az * a))));
      aw = fmaf(w0, xu[0].w, fmaf(w1, xu[1].w, fmaf(w2, xu[2].w, fmaf(w3, xu[3].w, aw * a))));
      m = mn;
    }
  }
  float inv = 1.f / s;
  float4 b4v = *reinterpret_cast<const float4*>(&bias[l16 * 4]);
  float4 hv  = *reinterpret_cast<const float4*>(&h_in[(size_t)v * D + l16 * 4]);
  float4 o;
  o.x = fmaxf(ax * inv + b4v.x, 0.f) + hv.x;
  o.y = fmaxf(ay * inv + b4v.y, 0.f) + hv.y;
  o.z = fmaxf(az * inv + b4v.z, 0.f) + hv.z;
  o.w = fmaxf(aw * inv + b4v.w, 0.f) + hv.w;
  *reinterpret_cast<float4*>(&h_out[(size_t)v * D + l16 * 4]) = o;
}

// ---------------- launch ----------------

extern "C" void kernel_launch(void* const* d_in, const int* in_sizes, int n_in,
                              void* d_out, int out_size, void* d_ws, size_t ws_size,
                              hipStream_t stream) {
  const float* x    = (const float*)d_in[0];
  const int*   ei   = (const int*)d_in[1];
  const float* Wl   = (const float*)d_in[2];
  const float* bl   = (const float*)d_in[3];
  const float* Wr   = (const float*)d_in[4];
  const float* br   = (const float*)d_in[5];
  const float* att  = (const float*)d_in[6];
  const float* bias = (const float*)d_in[7];

  int N = in_sizes[0] / D;
  int E = in_sizes[1] / 2;
  int L = in_sizes[2] / (D * D);
  int EP = E + N;
  int NC = (N + (1 << CB) - 1) >> CB;   // coarse buckets (<= 64)
  int M = NC * NBLK;

  float* hA = (float*)d_ws;
  float* hB = hA + (size_t)N * D;
  unsigned short* xlh = (unsigned short*)(hB + (size_t)N * D);
  unsigned short* xrh = xlh + (size_t)N * D;
  unsigned* rec = (unsigned*)(xrh + (size_t)N * D);
  unsigned short* csr_src = (unsigned short*)(rec + EP);
  int* rowptr   = (int*)(csr_src + ((EP + 1) & ~1));
  int* ghist    = rowptr + (N + 1);
  int* cbase    = ghist + M;

  // CSR build (graph is layer-invariant: build once per call; every ghist/cbase
  // slot is written each call, so no memset needed)
  hist_coarse_kernel<<<NBLK, 256, 0, stream>>>(ei, ghist, E, N, NC);
  scan_coarse_kernel<<<1, 1024, 0, stream>>>(ghist, cbase, M, NC, EP);
  scatter_coarse_kernel<<<NBLK, 256, 0, stream>>>(ei, ghist, rec, E, N, NC);
  buildcsr2_kernel<<<NC, 1024, 0, stream>>>(rec, cbase, rowptr, csr_src, N, EP);

  int nwaves = (N + 3) / 4;                 // 4 nodes per wave
  int nblocks = (nwaves * 64 + 255) / 256;
  const float* h_in = x;
  for (int l = 0; l < L; ++l) {
    float* h_out = (l == L - 1) ? (float*)d_out : ((l % 2 == 0) ? hA : hB);
    transform_kernel<<<(N + 15) / 16, 256, 0, stream>>>(
        h_in, Wl + (size_t)l * D * D, bl + (size_t)l * D,
        Wr + (size_t)l * D * D, br + (size_t)l * D, xlh, xrh, N);
    edge_kernel<<<nblocks, 256, 0, stream>>>(
        xlh, xrh, h_in, rowptr, csr_src, att + (size_t)l * D,
        bias + (size_t)l * D, h_out, N);
    h_in = h_out;
  }
}

// Round 9
// 205.805 us; speedup vs baseline: 1.3864x; 1.0621x over previous
//
#include <hip/hip_runtime.h>
#include <hip/hip_bf16.h>
#include <cmath>

// GATv2 encoder, 3 layers, d=64, f32 in/out.
//   1. dst-CSR build via two-level partition (coarse 1024-dst buckets ->
//      per-coarse-bucket fine CSR; csr_src as ushort), then a counting sort
//      of nodes by degree (perm) so each edge-kernel wave gets 4 equal-degree
//      nodes (kills intra-wave divergence).
//   2. per layer: persistent transform (W loaded once per block, grid-stride
//      over node tiles) -> xlh/xrh bf16 tables; edge aggregation: 4 nodes per
//      wave (16-lane groups), online softmax with defer-rescale (threshold 8),
//      bf16 gathers, prefetched ushort indices, fused bias+ReLU+residual.

#define D 64
#define CB 10              // coarse bucket = 1024 dsts (dst >> CB); N <= 65536
#define NBLK 512           // persistent blocks for coarse hist/scatter

// ---------------- CSR build ----------------

// C1: per-block coarse histogram. ghist[c*NBLK + blk] = count.
__global__ __launch_bounds__(256) void hist_coarse_kernel(
    const int* __restrict__ ei, int* __restrict__ ghist, int E, int N, int NC) {
  __shared__ int h[64];
  int tid = threadIdx.x, blk = blockIdx.x;
  if (tid < 64) h[tid] = 0;
  __syncthreads();
  for (int eid = blk * 256 + tid; eid < E + N; eid += NBLK * 256) {
    int d = (eid < E) ? ei[E + eid] : (eid - E);
    atomicAdd(&h[d >> CB], 1);
  }
  __syncthreads();
  if (tid < NC) ghist[tid * NBLK + blk] = h[tid];
}

// C2: exclusive scan of M = NC*NBLK counts in place; emit cbase; zero dh.
__global__ __launch_bounds__(1024) void scan_coarse_kernel(
    int* __restrict__ g, int* __restrict__ cbase, int* __restrict__ dh,
    int M, int NC, int EP) {
  int tid = threadIdx.x;
  if (tid < 64) dh[tid] = 0;              // degree-histogram init (used later)
  int chunk = (M + 1023) / 1024;
  int beg = tid * chunk;
  int end = min(M, beg + chunk);
  int sum = 0;
  for (int i = beg; i < end; ++i) sum += g[i];
  int lane = tid & 63, w = tid >> 6;
  int v = sum;
#pragma unroll
  for (int o = 1; o < 64; o <<= 1) {
    int t = __shfl_up(v, o, 64);
    if (lane >= o) v += t;
  }
  __shared__ int wsum[16], woff[16];
  if (lane == 63) wsum[w] = v;
  __syncthreads();
  if (tid == 0) { int r = 0; for (int i = 0; i < 16; ++i) { woff[i] = r; r += wsum[i]; } }
  __syncthreads();
  int run = woff[w] + (v - sum);
  for (int i = beg; i < end; ++i) {
    int old = g[i];
    g[i] = run;
    if ((i & (NBLK - 1)) == 0) cbase[i / NBLK] = run;
    run += old;
  }
  if (tid == 0) cbase[NC] = EP;
}

// C3: coarse scatter; per-(block,bucket) runs are contiguous -> full-line writes.
// rec = (dst&1023)<<16 | src.
__global__ __launch_bounds__(256) void scatter_coarse_kernel(
    const int* __restrict__ ei, const int* __restrict__ g,
    unsigned* __restrict__ rec, int E, int N, int NC) {
  __shared__ int cur[64];
  int tid = threadIdx.x, blk = blockIdx.x;
  if (tid < NC) cur[tid] = g[tid * NBLK + blk];
  __syncthreads();
  for (int eid = blk * 256 + tid; eid < E + N; eid += NBLK * 256) {
    int s, d;
    if (eid < E) { s = ei[eid]; d = ei[E + eid]; }
    else         { s = d = eid - E; }
    int pos = atomicAdd(&cur[d >> CB], 1);
    rec[pos] = ((unsigned)(d & ((1 << CB) - 1)) << 16) | (unsigned)s;
  }
}

// C4: one block per coarse bucket: LDS hist of 1024 dsts -> scan -> rowptr +
// scatter (ushort src) in the bucket's L2-local region; accumulate deg hist.
__global__ __launch_bounds__(1024) void buildcsr2_kernel(
    const unsigned* __restrict__ rec, const int* __restrict__ cbase,
    int* __restrict__ rowptr, unsigned short* __restrict__ csr_src,
    int* __restrict__ dh, int N, int EP) {
  int c = blockIdx.x, tid = threadIdx.x;
  int bb = cbase[c], be = cbase[c + 1];
  __shared__ int hist[1024], cur[1024];
  __shared__ int dloc[64];
  hist[tid] = 0;
  if (tid < 64) dloc[tid] = 0;
  __syncthreads();
  for (int p = bb + tid; p < be; p += 1024)
    atomicAdd(&hist[rec[p] >> 16], 1);
  __syncthreads();
  int dv = hist[tid];
  int lane = tid & 63, w = tid >> 6;
  int inc = dv;
#pragma unroll
  for (int o = 1; o < 64; o <<= 1) {
    int t = __shfl_up(inc, o, 64);
    if (lane >= o) inc += t;
  }
  __shared__ int wsum[16], woff[16];
  if (lane == 63) wsum[w] = inc;
  __syncthreads();
  if (tid == 0) { int r = 0; for (int i = 0; i < 16; ++i) { woff[i] = r; r += wsum[i]; } }
  __syncthreads();
  int excl = woff[w] + inc - dv;
  cur[tid] = excl;
  int node = (c << CB) + tid;
  if (node < N) {
    rowptr[node] = bb + excl;
    atomicAdd(&dloc[min(dv, 63)], 1);
  }
  if (c == 0 && tid == 0) rowptr[N] = EP;
  __syncthreads();
  if (tid < 64 && dloc[tid]) atomicAdd(&dh[tid], dloc[tid]);
  for (int p = bb + tid; p < be; p += 1024) {
    unsigned r = rec[p];
    int pos = bb + atomicAdd(&cur[r >> 16], 1);
    csr_src[pos] = (unsigned short)(r & 0xFFFFu);
  }
}

// C5: exclusive scan of the 64 degree bins -> dcur.
__global__ __launch_bounds__(64) void deg_scan_kernel(
    const int* __restrict__ dh, int* __restrict__ dcur) {
  int tid = threadIdx.x;
  int v = dh[tid];
  int orig = v;
#pragma unroll
  for (int o = 1; o < 64; o <<= 1) {
    int t = __shfl_up(v, o, 64);
    if (tid >= o) v += t;
  }
  dcur[tid] = v - orig;
}

// C6: scatter node ids into perm, grouped by degree bin (block-aggregated).
__global__ __launch_bounds__(256) void deg_scatter_kernel(
    const int* __restrict__ rowptr, int* __restrict__ dcur,
    int* __restrict__ perm, int N) {
  __shared__ int cnt[64], base[64], cur2[64];
  int tid = threadIdx.x;
  if (tid < 64) { cnt[tid] = 0; cur2[tid] = 0; }
  __syncthreads();
  int i = blockIdx.x * 256 + tid;
  int bin = 0;
  bool act = (i < N);
  if (act) {
    int deg = rowptr[i + 1] - rowptr[i];
    bin = min(deg, 63);
    atomicAdd(&cnt[bin], 1);
  }
  __syncthreads();
  if (tid < 64 && cnt[tid]) base[tid] = atomicAdd(&dcur[tid], cnt[tid]);
  __syncthreads();
  if (act) {
    int pos = base[bin] + atomicAdd(&cur2[bin], 1);
    perm[pos] = i;
  }
}

// ---------------- transform: xlh = bf16(h@Wl+bl), xrh = bf16(h@Wr+br) -------
// Persistent: W held in registers once per block; grid-stride over 16-node tiles.

__device__ __forceinline__ unsigned short f2bf(float f) {
  unsigned u = __float_as_uint(f);
  return (unsigned short)((u + 0x7FFFu + ((u >> 16) & 1u)) >> 16);  // RNE
}
__device__ __forceinline__ float bflo(unsigned u) { return __uint_as_float(u << 16); }
__device__ __forceinline__ float bfhi(unsigned u) { return __uint_as_float(u & 0xFFFF0000u); }

__global__ __launch_bounds__(256) void transform_kernel(
    const float* __restrict__ h,
    const float* __restrict__ Wl, const float* __restrict__ bl,
    const float* __restrict__ Wr, const float* __restrict__ br,
    unsigned short* __restrict__ xlh, unsigned short* __restrict__ xrh,
    int N, int ntiles) {
  __shared__ float hs[16][D];
  int tid = threadIdx.x;
  int j = tid & 63;
  float wl[D], wr[D];
#pragma unroll
  for (int k = 0; k < D; ++k) {           // coalesced: lane j reads column j
    wl[k] = Wl[k * D + j];
    wr[k] = Wr[k * D + j];
  }
  float blj = bl[j], brj = br[j];
  int nl = tid >> 6;
  int lr = tid >> 4, lc = (tid & 15) * 4; // float4 tile loader mapping
  for (int tile = blockIdx.x; tile < ntiles; tile += gridDim.x) {
    int node0 = tile * 16;
    __syncthreads();                      // hs safe to overwrite
    int n = node0 + lr;
    float4 hv4 = make_float4(0.f, 0.f, 0.f, 0.f);
    if (n < N) hv4 = *reinterpret_cast<const float4*>(&h[(size_t)n * D + lc]);
    *reinterpret_cast<float4*>(&hs[lr][lc]) = hv4;
    __syncthreads();
    for (int g = 0; g < 4; ++g) {
      int local = nl * 4 + g;
      int nn = node0 + local;
      float al = blj, ar = brj;
#pragma unroll
      for (int k4 = 0; k4 < D / 4; ++k4) {
        float4 hv = *reinterpret_cast<const float4*>(&hs[local][k4 * 4]);
        al = fmaf(hv.x, wl[k4 * 4 + 0], al);
        ar = fmaf(hv.x, wr[k4 * 4 + 0], ar);
        al = fmaf(hv.y, wl[k4 * 4 + 1], al);
        ar = fmaf(hv.y, wr[k4 * 4 + 1], ar);
        al = fmaf(hv.z, wl[k4 * 4 + 2], al);
        ar = fmaf(hv.z, wr[k4 * 4 + 2], ar);
        al = fmaf(hv.w, wl[k4 * 4 + 3], al);
        ar = fmaf(hv.w, wr[k4 * 4 + 3], ar);
      }
      if (nn < N) {
        xlh[(size_t)nn * D + j] = f2bf(al);
        xrh[(size_t)nn * D + j] = f2bf(ar);
      }
    }
  }
}

// ---------------- edge aggregation ----------------
// Wave = 4 equal-degree nodes (via perm); 16-lane group per node (float4
// features/lane, bf16 gathers). Online softmax over 4-edge chunks with
// defer-rescale (threshold 8). Fused bias+ReLU+residual.

__global__ __launch_bounds__(256) void edge_kernel(
    const unsigned short* __restrict__ xlh, const unsigned short* __restrict__ xrh,
    const float* __restrict__ h_in, const int* __restrict__ rowptr,
    const unsigned short* __restrict__ csr_src, const int* __restrict__ perm,
    const float* __restrict__ att, const float* __restrict__ bias,
    float* __restrict__ h_out, int N) {
  int wv = (blockIdx.x * blockDim.x + threadIdx.x) >> 6;
  int lane = threadIdx.x & 63;
  int g = lane >> 4, l16 = lane & 15;
  int idx = wv * 4 + g;
  if (idx >= N) return;
  int v = perm[idx];                         // equal-degree within the wave
  uint2 xq = *reinterpret_cast<const uint2*>(&xrh[(size_t)v * D + l16 * 4]);
  float4 xr4;
  xr4.x = bflo(xq.x); xr4.y = bfhi(xq.x);
  xr4.z = bflo(xq.y); xr4.w = bfhi(xq.y);
  float4 at4 = *reinterpret_cast<const float4*>(&att[l16 * 4]);
  int beg = rowptr[v], end = rowptr[v + 1];
  int deg = end - beg;                       // >= 1 (self-loop)
  int glane0 = g << 4;
  float m = -INFINITY, s = 0.f;
  float ax = 0.f, ay = 0.f, az = 0.f, aw = 0.f;
  int us = csr_src[min(beg + l16, end - 1)]; // first 16 srcs (coalesced)
  for (int sc = 0; sc < deg; sc += 16) {
    int us_cur = us;
    if (sc + 16 < deg)                       // prefetch next batch's indices
      us = csr_src[min(beg + sc + 16 + l16, end - 1)];
    int nt = min(16, deg - sc);
    for (int cc = 0; cc < nt; cc += 4) {
      float4 xu[4];
      float p[4];
#pragma unroll
      for (int k = 0; k < 4; ++k) {
        int u = __shfl(us_cur, glane0 + cc + k, 64);   // group-local broadcast
        uint2 q = *reinterpret_cast<const uint2*>(&xlh[(size_t)u * D + l16 * 4]);
        xu[k].x = bflo(q.x);
        xu[k].y = bfhi(q.x);
        xu[k].z = bflo(q.y);
        xu[k].w = bfhi(q.y);
        float tx = xu[k].x + xr4.x, ty = xu[k].y + xr4.y;
        float tz = xu[k].z + xr4.z, tw = xu[k].w + xr4.w;
        tx = fmaxf(tx, 0.2f * tx);                     // leaky_relu slope 0.2
        ty = fmaxf(ty, 0.2f * ty);
        tz = fmaxf(tz, 0.2f * tz);
        tw = fmaxf(tw, 0.2f * tw);
        float pp = tx * at4.x;
        pp = fmaf(ty, at4.y, pp);
        pp = fmaf(tz, at4.z, pp);
        pp = fmaf(tw, at4.w, pp);
        pp += __shfl_xor(pp, 1, 64);                   // 16-lane group reduce
        pp += __shfl_xor(pp, 2, 64);
        pp += __shfl_xor(pp, 4, 64);
        pp += __shfl_xor(pp, 8, 64);
        p[k] = (cc + k < nt) ? pp : -INFINITY;
      }
      float pm = fmaxf(fmaxf(p[0], p[1]), fmaxf(p[2], p[3]));
      if (pm > m + 8.0f) {                   // defer-rescale (group-uniform)
        float a = __expf(m - pm);            // first chunk: exp(-inf)=0
        s *= a; ax *= a; ay *= a; az *= a; aw *= a;
        m = pm;
      }
      float w0 = __expf(p[0] - m);           // bounded by e^8; invalid -> 0
      float w1 = __expf(p[1] - m);
      float w2 = __expf(p[2] - m);
      float w3 = __expf(p[3] - m);
      s += (w0 + w1) + (w2 + w3);
      ax = fmaf(w0, xu[0].x, fmaf(w1, xu[1].x, fmaf(w2, xu[2].x, fmaf(w3, xu[3].x, ax))));
      ay = fmaf(w0, xu[0].y, fmaf(w1, xu[1].y, fmaf(w2, xu[2].y, fmaf(w3, xu[3].y, ay))));
      az = fmaf(w0, xu[0].z, fmaf(w1, xu[1].z, fmaf(w2, xu[2].z, fmaf(w3, xu[3].z, az))));
      aw = fmaf(w0, xu[0].w, fmaf(w1, xu[1].w, fmaf(w2, xu[2].w, fmaf(w3, xu[3].w, aw))));
    }
  }
  float inv = 1.f / s;
  float4 b4v = *reinterpret_cast<const float4*>(&bias[l16 * 4]);
  float4 hv  = *reinterpret_cast<const float4*>(&h_in[(size_t)v * D + l16 * 4]);
  float4 o;
  o.x = fmaxf(ax * inv + b4v.x, 0.f) + hv.x;
  o.y = fmaxf(ay * inv + b4v.y, 0.f) + hv.y;
  o.z = fmaxf(az * inv + b4v.z, 0.f) + hv.z;
  o.w = fmaxf(aw * inv + b4v.w, 0.f) + hv.w;
  *reinterpret_cast<float4*>(&h_out[(size_t)v * D + l16 * 4]) = o;
}

// ---------------- launch ----------------

extern "C" void kernel_launch(void* const* d_in, const int* in_sizes, int n_in,
                              void* d_out, int out_size, void* d_ws, size_t ws_size,
                              hipStream_t stream) {
  const float* x    = (const float*)d_in[0];
  const int*   ei   = (const int*)d_in[1];
  const float* Wl   = (const float*)d_in[2];
  const float* bl   = (const float*)d_in[3];
  const float* Wr   = (const float*)d_in[4];
  const float* br   = (const float*)d_in[5];
  const float* att  = (const float*)d_in[6];
  const float* bias = (const float*)d_in[7];

  int N = in_sizes[0] / D;
  int E = in_sizes[1] / 2;
  int L = in_sizes[2] / (D * D);
  int EP = E + N;
  int NC = (N + (1 << CB) - 1) >> CB;   // coarse buckets (<= 64)
  int M = NC * NBLK;

  float* hA = (float*)d_ws;
  float* hB = hA + (size_t)N * D;
  unsigned short* xlh = (unsigned short*)(hB + (size_t)N * D);
  unsigned short* xrh = xlh + (size_t)N * D;
  unsigned* rec = (unsigned*)(xrh + (size_t)N * D);
  unsigned short* csr_src = (unsigned short*)(rec + EP);
  int* rowptr   = (int*)(csr_src + ((EP + 1) & ~1));
  int* ghist    = rowptr + (N + 1);
  int* cbase    = ghist + M;
  int* dh       = cbase + (NC + 1);
  int* dcur     = dh + 64;
  int* perm     = dcur + 64;

  // CSR build + degree sort (graph is layer-invariant: once per call; every
  // slot used is rewritten each call, so no memsets needed)
  hist_coarse_kernel<<<NBLK, 256, 0, stream>>>(ei, ghist, E, N, NC);
  scan_coarse_kernel<<<1, 1024, 0, stream>>>(ghist, cbase, dh, M, NC, EP);
  scatter_coarse_kernel<<<NBLK, 256, 0, stream>>>(ei, ghist, rec, E, N, NC);
  buildcsr2_kernel<<<NC, 1024, 0, stream>>>(rec, cbase, rowptr, csr_src, dh, N, EP);
  deg_scan_kernel<<<1, 64, 0, stream>>>(dh, dcur);
  deg_scatter_kernel<<<(N + 255) / 256, 256, 0, stream>>>(rowptr, dcur, perm, N);

  int ntiles = (N + 15) / 16;
  int nwaves = (N + 3) / 4;                 // 4 nodes per wave
  int nblocks = (nwaves * 64 + 255) / 256;
  const float* h_in = x;
  for (int l = 0; l < L; ++l) {
    float* h_out = (l == L - 1) ? (float*)d_out : ((l % 2 == 0) ? hA : hB);
    transform_kernel<<<512, 256, 0, stream>>>(
        h_in, Wl + (size_t)l * D * D, bl + (size_t)l * D,
        Wr + (size_t)l * D * D, br + (size_t)l * D, xlh, xrh, N, ntiles);
    edge_kernel<<<nblocks, 256, 0, stream>>>(
        xlh, xrh, h_in, rowptr, csr_src, perm, att + (size_t)l * D,
        bias + (size_t)l * D, h_out, N);
    h_in = h_out;
  }
}